// Round 16
// baseline (1138.158 us; speedup 1.0000x reference)
//
#include <hip/hip_runtime.h>
#include <stdint.h>
#include <stddef.h>

typedef __attribute__((ext_vector_type(8))) short bf16x8;
typedef __attribute__((ext_vector_type(4))) float f32x4;
typedef unsigned short u16;
typedef unsigned int u32;
typedef unsigned long long u64;

static constexpr int S_ = 2048, B_ = 2, H_ = 2048, NH_ = 16, D_ = 128, M_ = 2048, FF_ = 8192;
static constexpr int SB_ = S_ * B_;
static constexpr int MB_ = M_ * B_;

__device__ __forceinline__ float b2f(u16 b) {
  union { u32 u; float f; } v; v.u = ((u32)b) << 16; return v.f;
}
__device__ __forceinline__ u16 f2b(float f) {
  union { float f; u32 u; } v; v.f = f;
  u32 u = v.u;
  return (u16)((u + 0x7FFFu + ((u >> 16) & 1u)) >> 16);
}
__device__ __forceinline__ float geluf(float x) {
  float x3 = x * x * x;
  return 0.5f * x * (1.0f + tanhf(0.7978845608028654f * (x + 0.044715f * x3)));
}

#define LDSP(p) (reinterpret_cast<__attribute__((address_space(3))) uint32_t*>(reinterpret_cast<uintptr_t>(p)))
#define GLBP(p) (reinterpret_cast<const __attribute__((address_space(1))) uint32_t*>(reinterpret_cast<uintptr_t>(p)))

// ---------------------------------------------------------------- detectors
__global__ void detect_kinds(const u32* __restrict__ x0, const u32* __restrict__ mask, int* __restrict__ flags) {
  if (threadIdx.x == 0 && blockIdx.x == 0) {
    int cnt = 0;
    for (int i = 0; i < 256; ++i) {
      u32 e = (x0[i] >> 7) & 0xFFu;
      if (e >= 118u && e <= 130u) ++cnt;
    }
    flags[0] = (cnt >= 128) ? 0 : 1;
    int all01 = 1, allf = 1, allb = 1;
    for (int i = 0; i < 256; ++i) {
      u32 v = mask[i];
      if (v > 1u) all01 = 0;
      if (v != 0u && v != 0x3F800000u) allf = 0;
      u32 lo = v & 0xFFFFu, hi = v >> 16;
      if ((lo != 0u && lo != 0x3F80u) || (hi != 0u && hi != 0x3F80u)) allb = 0;
    }
    flags[1] = all01 ? 1 : (allf ? 3 : (allb ? 2 : 0));
  }
}

// mask -> packed bitmask: bit m = 1 iff UNMASKED
__global__ void mask_bits(const void* __restrict__ mraw, const int* __restrict__ flags, u64* __restrict__ bm) {
  int i = blockIdx.x * 256 + threadIdx.x;
  int kind = flags[1];
  int masked;
  if (kind == 1)      masked = ((const int*)mraw)[i] != 0;
  else if (kind == 3) masked = ((const float*)mraw)[i] != 0.0f;
  else if (kind == 2) masked = ((const u16*)mraw)[i] != 0;
  else                masked = ((const unsigned char*)mraw)[i] != 0;
  u64 vote = __ballot(masked == 0);
  if ((threadIdx.x & 63) == 0) bm[i >> 6] = vote;
}

// one launch for all 13 small f32 param conversions
__global__ void cvt_all(const void* s0, const void* s1, const void* s2, const void* s3,
                        const void* s4, const void* s5, const void* s6, const void* s7,
                        const void* s8, const void* s9, const void* s10, const void* s11,
                        const void* s12, const int* __restrict__ flags, float* __restrict__ SM) {
  const int i = blockIdx.x * 256 + threadIdx.x;
  if (i >= 40960) return;
  const void* src; int off;
  if (i < 8192)       { src = s0;  off = 0; }
  else if (i < 10240) { src = s1;  off = 8192; }
  else if (i < 12288) { src = s2;  off = 10240; }
  else if (i < 16384) { src = s3;  off = 12288; }
  else if (i < 18432) { src = s4;  off = 16384; }
  else if (i < 26624) { src = s5;  off = 18432; }
  else if (i < 28672) { src = s6;  off = 26624; }
  else if (i < 30720) { src = s7;  off = 28672; }
  else if (i < 32768) { src = s8;  off = 30720; }
  else if (i < 34816) { src = s9;  off = 32768; }
  else if (i < 36864) { src = s10; off = 34816; }
  else if (i < 38912) { src = s11; off = 36864; }
  else                { src = s12; off = 38912; }
  const int j = i - off;
  SM[i] = flags[0] ? ((const float*)src)[j] : b2f(((const u16*)src)[j]);
}

__global__ void cast_in_bf16(const void* __restrict__ src, const int* __restrict__ flags, u16* __restrict__ dst, int n8) {
  int i = blockIdx.x * 256 + threadIdx.x;
  if (i >= n8) return;
  if (flags[0]) {
    const float4* p = (const float4*)src;
    float4 a = p[i * 2], c = p[i * 2 + 1];
    bf16x8 o;
    o[0] = (short)f2b(a.x); o[1] = (short)f2b(a.y); o[2] = (short)f2b(a.z); o[3] = (short)f2b(a.w);
    o[4] = (short)f2b(c.x); o[5] = (short)f2b(c.y); o[6] = (short)f2b(c.z); o[7] = (short)f2b(c.w);
    *(bf16x8*)&dst[i * 8] = o;
  } else {
    *(bf16x8*)&dst[i * 8] = ((const bf16x8*)src)[i];
  }
}

// ------------------------------------------------------------ transpose+cast
__global__ __launch_bounds__(256) void transpose_cast(const void* __restrict__ in, const int* __restrict__ flags,
                                                      u16* __restrict__ out, int R, int C) {
  __shared__ u16 tile[64][65];
  const int isf = flags[0];
  const int tr = blockIdx.y * 64, tc = blockIdx.x * 64;
  const int tx = threadIdx.x & 63, ty = threadIdx.x >> 6;
  const float* inf = (const float*)in;
  const u16* inb = (const u16*)in;
#pragma unroll
  for (int i = 0; i < 16; ++i) {
    int r = ty * 16 + i;
    size_t idx = (size_t)(tr + r) * C + tc + tx;
    tile[r][tx] = isf ? f2b(inf[idx]) : inb[idx];
  }
  __syncthreads();
#pragma unroll
  for (int i = 0; i < 16; ++i) {
    int c = ty * 16 + i;
    out[(size_t)(tc + c) * R + tr + tx] = tile[tx][c];
  }
}

// ---------------------------------------------------------------- layernorm
template <int EXT>
__global__ __launch_bounds__(256) void layernorm_k(const void* __restrict__ xin, const int* __restrict__ flags,
                                                   const float* __restrict__ g, const float* __restrict__ bta,
                                                   u16* __restrict__ out) {
  const int row = blockIdx.x, t = threadIdx.x;
  float v[8];
  bool bfmode = EXT && (flags[0] == 0);
  if (bfmode) {
    const u16* xr = (const u16*)xin + (size_t)row * H_ + t * 8;
    bf16x8 a = *(const bf16x8*)xr;
#pragma unroll
    for (int j = 0; j < 8; ++j) v[j] = b2f((u16)a[j]);
  } else {
    const float* xr = (const float*)xin + (size_t)row * H_ + t * 8;
    float4 a = *(const float4*)xr, c = *(const float4*)(xr + 4);
    v[0] = a.x; v[1] = a.y; v[2] = a.z; v[3] = a.w;
    v[4] = c.x; v[5] = c.y; v[6] = c.z; v[7] = c.w;
  }
  float s1 = 0.f, s2 = 0.f;
#pragma unroll
  for (int j = 0; j < 8; ++j) { s1 += v[j]; s2 += v[j] * v[j]; }
#pragma unroll
  for (int off = 32; off > 0; off >>= 1) { s1 += __shfl_down(s1, off); s2 += __shfl_down(s2, off); }
  __shared__ float red[8];
  const int w = t >> 6;
  if ((t & 63) == 0) { red[w] = s1; red[4 + w] = s2; }
  __syncthreads();
  s1 = red[0] + red[1] + red[2] + red[3];
  s2 = red[4] + red[5] + red[6] + red[7];
  const float mean = s1 * (1.0f / H_);
  const float rstd = rsqrtf(s2 * (1.0f / H_) - mean * mean + 1e-5f);
  bf16x8 o;
#pragma unroll
  for (int j = 0; j < 8; ++j) {
    float y = (v[j] - mean) * rstd * g[t * 8 + j] + bta[t * 8 + j];
    o[j] = (short)f2b(y);
  }
  *(bf16x8*)(out + (size_t)row * H_ + t * 8) = o;
}

// ------------------------------------------------------------------- GEMM
// gemmra512 (round-13 winner) + fused l2-norm epilogues (round-15).
template <int GELU, int RES, int WF, int WB, int ODYN, int EPI>
__global__ __launch_bounds__(512, 2) void gemmra512(const u16* __restrict__ A, const u16* __restrict__ Bt,
                                                    const float* __restrict__ bias, const float* __restrict__ res,
                                                    void* __restrict__ outF, u16* __restrict__ outB,
                                                    const int* __restrict__ flags, int Mr, int N, int K) {
  __shared__ u16 lds[32768];   // 64 KiB
  const int t = threadIdx.x;
  const int w = t >> 6, l = t & 63, lr = l & 15, lk = l >> 4;
  const int wr = w >> 2, wc = w & 3;
  const int gx = gridDim.x, gy = gridDim.y;
  const int orig = blockIdx.y * gx + blockIdx.x;
  const int nwg = gx * gy, per = nwg >> 3;
  int tm, tn;
  if ((gx & 7) == 0 && (per & 7) == 0) {
    const int xcd = orig & 7, p = orig >> 3;
    const int ncx = gx >> 3, cy = per >> 3;
    const int ccol = xcd % ncx, crow = xcd / ncx;
    const int px = p & 7, py = p >> 3;
    tn = (ccol * 8 + px) * 128;
    tm = (crow * cy + py) * 128;
  } else {
    tn = (orig % gx) * 128;
    tm = (orig / gx) * 128;
  }
  u32 aofs[2], bofs[2];
#pragma unroll
  for (int i = 0; i < 2; ++i) {
    const int idx = i * 512 + t;
    const int srow = idx >> 3, sc = idx & 7;
    const int lc = sc ^ (srow & 7);
    aofs[i] = (u32)(tm + srow) * (u32)K + (u32)lc * 8;
    bofs[i] = (u32)(tn + srow) * (u32)K + (u32)lc * 8;
  }
  const int wdst = w * 512;
  const int cso0 = ((0 + lk) ^ (lr & 7)) * 8;
  const int cso1 = ((4 + lk) ^ (lr & 7)) * 8;
  int arow[4], brow[2];
#pragma unroll
  for (int f = 0; f < 4; ++f) arow[f] = (wr * 64 + f * 16 + lr) * 64;
#pragma unroll
  for (int f = 0; f < 2; ++f) brow[f] = (wc * 32 + f * 16 + lr) * 64;

  const int NS = K >> 6;
  f32x4 acc[4][2] = {};

#define STG(sl) do {                                                                                  \
    u16* Ad = lds + ((sl) & 1) * 16384;                                                               \
    u16* Bd = Ad + 8192;                                                                              \
    const u32 ko = (u32)(sl) * 64;                                                                    \
    _Pragma("unroll")                                                                                 \
    for (int i = 0; i < 2; ++i) {                                                                     \
      __builtin_amdgcn_global_load_lds(GLBP(A + aofs[i] + ko), LDSP(Ad + i * 4096 + wdst), 16, 0, 0); \
      __builtin_amdgcn_global_load_lds(GLBP(Bt + bofs[i] + ko), LDSP(Bd + i * 4096 + wdst), 16, 0, 0);\
    }                                                                                                 \
  } while (0)
#define RD(afX, bqX, sl, cso) do {                                                                    \
    const u16* As_ = lds + ((sl) & 1) * 16384;                                                        \
    const u16* Bs_ = As_ + 8192;                                                                      \
    _Pragma("unroll")                                                                                 \
    for (int f = 0; f < 4; ++f) afX[f] = *(const bf16x8*)(As_ + arow[f] + (cso));                     \
    _Pragma("unroll")                                                                                 \
    for (int f = 0; f < 2; ++f) bqX[f] = *(const bf16x8*)(Bs_ + brow[f] + (cso));                     \
  } while (0)
#define MM(afX, bqX)                                                                                  \
  _Pragma("unroll") for (int nf = 0; nf < 2; ++nf)                                                    \
  _Pragma("unroll") for (int mf = 0; mf < 4; ++mf)                                                    \
    acc[mf][nf] = __builtin_amdgcn_mfma_f32_16x16x32_bf16(afX[mf], bqX[nf], acc[mf][nf], 0, 0, 0);

  bf16x8 afA[4], bqA[2], afB[4], bqB[2];

  STG(0);
  asm volatile("s_waitcnt vmcnt(0)" ::: "memory");
  __builtin_amdgcn_s_barrier();
  RD(afA, bqA, 0, cso0);
  asm volatile("s_waitcnt lgkmcnt(0)" ::: "memory");
  __builtin_amdgcn_sched_barrier(0);

  for (int s = 0; s < NS; ++s) {
    if (s + 1 < NS) STG(s + 1);
    RD(afB, bqB, s, cso1);
    __builtin_amdgcn_sched_barrier(0);
    __builtin_amdgcn_s_setprio(1);
    MM(afA, bqA);
    __builtin_amdgcn_s_setprio(0);
    asm volatile("s_waitcnt lgkmcnt(0)" ::: "memory");
    __builtin_amdgcn_sched_barrier(0);
    asm volatile("s_waitcnt vmcnt(0)" ::: "memory");
    __builtin_amdgcn_s_barrier();
    if (s + 1 < NS) RD(afA, bqA, s + 1, cso0);
    __builtin_amdgcn_sched_barrier(0);
    __builtin_amdgcn_s_setprio(1);
    MM(afB, bqB);
    __builtin_amdgcn_s_setprio(0);
    asm volatile("s_waitcnt lgkmcnt(0)" ::: "memory");
    __builtin_amdgcn_sched_barrier(0);
  }
#undef STG
#undef RD
#undef MM

  (void)Mr;
  if constexpr (EPI == 0) {
    const int obf = ODYN ? (flags[0] ? 0 : 1) : 0;
#pragma unroll
    for (int mf = 0; mf < 4; ++mf) {
#pragma unroll
      for (int nf = 0; nf < 2; ++nf) {
        const int col = tn + wc * 32 + nf * 16 + lr;
        const float bv = bias[col];
#pragma unroll
        for (int j = 0; j < 4; ++j) {
          const int rw = tm + wr * 64 + mf * 16 + lk * 4 + j;
          float vv = acc[mf][nf][j] + bv;
          if (RES) vv += res[(size_t)rw * N + col];
          if (GELU) vv = geluf(vv);
          if (WF) {
            if (ODYN && obf) ((u16*)outF)[(size_t)rw * N + col] = f2b(vv);
            else ((float*)outF)[(size_t)rw * N + col] = vv;
          }
          if (WB) outB[(size_t)rw * N + col] = f2b(vv);
        }
      }
    }
  } else {
    float* red = reinterpret_cast<float*>(lds);
    u16* vt = lds + 4096;
    float bv2[2];
#pragma unroll
    for (int nf = 0; nf < 2; ++nf) bv2[nf] = bias[tn + wc * 32 + nf * 16 + lr];
    float ss[4][4];
#pragma unroll
    for (int mf = 0; mf < 4; ++mf)
#pragma unroll
      for (int j = 0; j < 4; ++j) {
        float s = 0.f;
#pragma unroll
        for (int nf = 0; nf < 2; ++nf) {
          float v = acc[mf][nf][j] + bv2[nf];
          s += v * v;
        }
        s += __shfl_xor(s, 1); s += __shfl_xor(s, 2); s += __shfl_xor(s, 4); s += __shfl_xor(s, 8);
        ss[mf][j] = s;
      }
    if (lr == 0) {
#pragma unroll
      for (int mf = 0; mf < 4; ++mf)
#pragma unroll
        for (int j = 0; j < 4; ++j) {
          const int row = wr * 64 + mf * 16 + lk * 4 + j;
          red[row * 4 + wc] = ss[mf][j];
        }
    }
    __syncthreads();
    float rs[4][4];
#pragma unroll
    for (int mf = 0; mf < 4; ++mf)
#pragma unroll
      for (int j = 0; j < 4; ++j) {
        const int row = wr * 64 + mf * 16 + lk * 4 + j;
        rs[mf][j] = rsqrtf(red[row * 4 + 0] + red[row * 4 + 1] + red[row * 4 + 2] + red[row * 4 + 3] + 1e-12f);
      }
    if constexpr (EPI == 1) {
      const int h = tn >> 7;
#pragma unroll
      for (int mf = 0; mf < 4; ++mf)
#pragma unroll
        for (int nf = 0; nf < 2; ++nf) {
          const int d = wc * 32 + nf * 16 + lr;
#pragma unroll
          for (int j = 0; j < 4; ++j) {
            const int rw = tm + wr * 64 + mf * 16 + lk * 4 + j;
            const int sR = rw >> 1, bb = rw & 1;
            float v = (acc[mf][nf][j] + bv2[nf]) * rs[mf][j];
            outB[(((size_t)(bb * NH_ + h) * S_) + sR) * D_ + d] = f2b(v);
          }
        }
    } else {
      const int h = tn >> 8;
      const int isV = (tn >> 7) & 1;
      if (!isV) {
#pragma unroll
        for (int mf = 0; mf < 4; ++mf)
#pragma unroll
          for (int nf = 0; nf < 2; ++nf) {
            const int d = wc * 32 + nf * 16 + lr;
#pragma unroll
            for (int j = 0; j < 4; ++j) {
              const int rw = tm + wr * 64 + mf * 16 + lk * 4 + j;
              const int mR = rw >> 1, bb = rw & 1;
              float v = (acc[mf][nf][j] + bv2[nf]) * rs[mf][j];
              outB[(((size_t)(bb * NH_ + h) * M_) + mR) * D_ + d] = f2b(v);
            }
          }
      } else {
#pragma unroll
        for (int mf = 0; mf < 4; ++mf)
#pragma unroll
          for (int nf = 0; nf < 2; ++nf) {
            const int d = wc * 32 + nf * 16 + lr;
#pragma unroll
            for (int j = 0; j < 4; ++j) {
              const int rl = wr * 64 + mf * 16 + lk * 4 + j;
              float v = (acc[mf][nf][j] + bv2[nf]) * rs[mf][j];
              vt[((rl & 1) * 128 + d) * 72 + (rl >> 1)] = f2b(v);
            }
          }
        __syncthreads();
        const int dd = t >> 2, bb = (t >> 1) & 1, half = t & 1;
        const u16* src = vt + ((size_t)(bb * 128 + dd) * 72) + half * 32;
        u16* dst = (u16*)outF + (((size_t)(bb * NH_ + h) * D_ + dd) * M_) + (tm >> 1) + half * 32;
#pragma unroll
        for (int i = 0; i < 4; ++i) *(bf16x8*)&dst[i * 8] = *(const bf16x8*)&src[i * 8];
      }
    }
  }
}

// gemmk32: A/B EXPERIMENT — max-occupancy variant.  Same 128x128 tile,
// 512 thr = 8 waves (2M x 4N, 64x32/wave), but BK=32 with 2-slot buffer =
// 32KB LDS -> 4 blocks/CU = 32 waves/CU = 8 waves/SIMD (max TLP).
// Packed super-row LDS (2 K-rows per 128B line, XOR swizzle; r5-measured
// conflict-free); 1 gload_lds chunk/thread/operand/slice; 1 barrier +
// vmcnt(0) per slice.  __launch_bounds__(512,8) caps VGPR at 64.
template <int GELU, int WB>
__global__ __launch_bounds__(512, 8) void gemmk32(const u16* __restrict__ A, const u16* __restrict__ Bt,
                                                  const float* __restrict__ bias,
                                                  u16* __restrict__ outB, int N, int K) {
  __shared__ u16 lds[16384];   // 32 KiB: 2 slots x (A 8KB + B 8KB)
  const int t = threadIdx.x;
  const int w = t >> 6, l = t & 63, lr = l & 15, lk = l >> 4;
  const int wr = w >> 2, wc = w & 3;
  const int gx = gridDim.x, gy = gridDim.y;
  const int orig = blockIdx.y * gx + blockIdx.x;
  const int nwg = gx * gy, per = nwg >> 3;
  int tm, tn;
  if ((gx & 7) == 0 && (per & 7) == 0) {
    const int xcd = orig & 7, p = orig >> 3;
    const int ncx = gx >> 3, cy = per >> 3;
    const int ccol = xcd % ncx, crow = xcd / ncx;
    const int px = p & 7, py = p >> 3;
    tn = (ccol * 8 + px) * 128;
    tm = (crow * cy + py) * 128;
  } else {
    tn = (orig % gx) * 128;
    tm = (orig / gx) * 128;
  }
  // staging: 512 chunks per operand per slice, 1 per thread.
  // chunk idx t: sr = t>>3, stored p' = t&7; logical p = p' ^ (sr&7);
  // row = (sr<<1)|(p>>2), ck = p&3.
  u32 aofs, bofs;
  {
    const int sr = t >> 3, pp = t & 7;
    const int p = pp ^ (sr & 7);
    const int row = (sr << 1) | (p >> 2), ck = p & 3;
    aofs = (u32)(tm + row) * (u32)K + (u32)ck * 8;
    bofs = (u32)(tn + row) * (u32)K + (u32)ck * 8;
  }
  const int wdst = w * 512;   // u16: wave's 64-chunk block
  // ds_read offsets: row R, k-chunk lk; sr=R>>1, p=((R&1)<<2)|lk, p'=p^(sr&7)
  int arow[4], brow[2];
#pragma unroll
  for (int f = 0; f < 4; ++f) {
    const int R = wr * 64 + f * 16 + lr, sr = R >> 1;
    arow[f] = sr * 64 + (((((R & 1) << 2) | lk) ^ (sr & 7)) << 3);
  }
#pragma unroll
  for (int f = 0; f < 2; ++f) {
    const int R = wc * 32 + f * 16 + lr, sr = R >> 1;
    brow[f] = sr * 64 + (((((R & 1) << 2) | lk) ^ (sr & 7)) << 3);
  }

  const int NS = K >> 5;
  f32x4 acc[4][2] = {};

#define STG(sl) do {                                                                                   \
    u16* Ad = lds + ((sl) & 1) * 8192;                                                                 \
    u16* Bd = Ad + 4096;                                                                               \
    const u32 ko = (u32)(sl) * 32;                                                                     \
    __builtin_amdgcn_global_load_lds(GLBP(A + aofs + ko), LDSP(Ad + wdst), 16, 0, 0);                  \
    __builtin_amdgcn_global_load_lds(GLBP(Bt + bofs + ko), LDSP(Bd + wdst), 16, 0, 0);                 \
  } while (0)
#define RD(afX, bqX, sl) do {                                                                          \
    const u16* As_ = lds + ((sl) & 1) * 8192;                                                          \
    const u16* Bs_ = As_ + 4096;                                                                       \
    _Pragma("unroll")                                                                                  \
    for (int f = 0; f < 4; ++f) afX[f] = *(const bf16x8*)(As_ + arow[f]);                              \
    _Pragma("unroll")                                                                                  \
    for (int f = 0; f < 2; ++f) bqX[f] = *(const bf16x8*)(Bs_ + brow[f]);                              \
  } while (0)
#define MM(afX, bqX)                                                                                   \
  _Pragma("unroll") for (int nf = 0; nf < 2; ++nf)                                                     \
  _Pragma("unroll") for (int mf = 0; mf < 4; ++mf)                                                     \
    acc[mf][nf] = __builtin_amdgcn_mfma_f32_16x16x32_bf16(afX[mf], bqX[nf], acc[mf][nf], 0, 0, 0);

  bf16x8 af[4], bq[2];

  STG(0);
  asm volatile("s_waitcnt vmcnt(0)" ::: "memory");
  __builtin_amdgcn_s_barrier();
  RD(af, bq, 0);

  for (int s = 0; s < NS; ++s) {
    if (s + 1 < NS) STG(s + 1);
    __builtin_amdgcn_sched_barrier(0);
    __builtin_amdgcn_s_setprio(1);
    MM(af, bq);
    __builtin_amdgcn_s_setprio(0);
    asm volatile("s_waitcnt vmcnt(0)" ::: "memory");
    __builtin_amdgcn_s_barrier();
    if (s + 1 < NS) RD(af, bq, s + 1);
    __builtin_amdgcn_sched_barrier(0);
  }
#undef STG
#undef RD
#undef MM

#pragma unroll
  for (int mf = 0; mf < 4; ++mf) {
#pragma unroll
    for (int nf = 0; nf < 2; ++nf) {
      const int col = tn + wc * 32 + nf * 16 + lr;
      const float bv = bias[col];
#pragma unroll
      for (int j = 0; j < 4; ++j) {
        const int rw = tm + wr * 64 + mf * 16 + lk * 4 + j;
        float vv = acc[mf][nf][j] + bv;
        if (GELU) vv = geluf(vv);
        if (WB) outB[(size_t)rw * N + col] = f2b(vv);
      }
    }
  }
}

// -------------------------------------------------------------- attention
// unchanged (verified; ~130 us)
__global__ __launch_bounds__(256, 3) void attn_k(const u16* __restrict__ Q, const u16* __restrict__ Kq,
                                                 const u16* __restrict__ Vt, const u32* __restrict__ BM32,
                                                 u16* __restrict__ ctx) {
  __shared__ u16 Kl[2][4096];
  __shared__ u16 Vl[2][4096];
  __shared__ u16 Pl[4][16 * 40];
  const int t = threadIdx.x, w = t >> 6, l = t & 63, lr = l & 15, lk = l >> 4;
  const int lin = blockIdx.x;
  const int xcd = lin & 7, idx = lin >> 3;
  const int bh = xcd * 4 + (idx >> 5);
  const int chunk = idx & 31;
  const int b = bh >> 4, h = bh & 15;
  const int srow = chunk * 64 + w * 16;
  const u16* Qb = Q + ((size_t)bh * S_ + srow) * D_;
  bf16x8 qf[4];
#pragma unroll
  for (int kc = 0; kc < 4; ++kc)
    qf[kc] = *(const bf16x8*)&Qb[lr * D_ + kc * 32 + lk * 8];
  f32x4 oacc[8] = {};
  float den[4] = {};
  const u16* Kb = Kq + (size_t)bh * M_ * D_;
  const u16* Vb = Vt + (size_t)bh * D_ * M_;
  const float invn = 0.08838834764831845f;
  u32 ksrc[2], vsrc[2];
#pragma unroll
  for (int i = 0; i < 2; ++i) {
    const int kidx = i * 256 + t;
    const int kr = kidx >> 4, kc_ = (kidx & 15) ^ (kr & 7);
    ksrc[i] = (u32)kr * D_ + (u32)kc_ * 8;
    const int vidx = i * 256 + t;
    const int vd = vidx >> 2, vc = (vidx & 3) ^ ((vd >> 1) & 3);
    vsrc[i] = (u32)vd * M_ + (u32)vc * 8;
  }
  const int wdst = w * 64 * 8;
  u32 mrow[4];
#pragma unroll
  for (int j2 = 0; j2 < 4; ++j2)
    mrow[j2] = ((u32)b * S_ + (u32)(srow + lk * 4 + j2)) * 64u;

#define STG(buf, m0) do {                                                                              \
    _Pragma("unroll")                                                                                  \
    for (int i = 0; i < 2; ++i) {                                                                      \
      __builtin_amdgcn_global_load_lds(GLBP(Kb + (size_t)(m0) * D_ + ksrc[i]),                         \
                                       LDSP(&Kl[buf][i * 2048 + wdst]), 16, 0, 0);                     \
      __builtin_amdgcn_global_load_lds(GLBP(Vb + (size_t)(m0) + vsrc[i]),                              \
                                       LDSP(&Vl[buf][i * 2048 + wdst]), 16, 0, 0);                     \
    }                                                                                                  \
  } while (0)

  STG(0, 0);
  asm volatile("s_waitcnt vmcnt(0)" ::: "memory");
  __builtin_amdgcn_s_barrier();
  int cur = 0;

  for (int t64 = 0; t64 < M_ / 32; ++t64) {
    const int m0 = t64 * 32;
    if (t64 + 1 < M_ / 32) STG(cur ^ 1, m0 + 32);
    u32 mw[4];
#pragma unroll
    for (int j2 = 0; j2 < 4; ++j2) mw[j2] = BM32[mrow[j2] + t64];
    f32x4 sc[2] = {};
#pragma unroll
    for (int mf = 0; mf < 2; ++mf) {
      const int r = mf * 16 + lr;
#pragma unroll
      for (int kc = 0; kc < 4; ++kc) {
        const int cc = ((kc * 4 + lk) ^ (r & 7));
        bf16x8 kfv = *(const bf16x8*)&Kl[cur][r * 128 + cc * 8];
        sc[mf] = __builtin_amdgcn_mfma_f32_16x16x32_bf16(qf[kc], kfv, sc[mf], 0, 0, 0);
      }
    }
#pragma unroll
    for (int j2 = 0; j2 < 4; ++j2) {
      const int rloc = lk * 4 + j2;
#pragma unroll
      for (int mf = 0; mf < 2; ++mf) {
        float p = __expf(sc[mf][j2] * invn);
        p = ((mw[j2] >> (mf * 16 + lr)) & 1u) ? p : 0.0f;
        den[j2] += p;
        Pl[w][rloc * 40 + mf * 16 + lr] = f2b(p);
      }
    }
    asm volatile("s_waitcnt lgkmcnt(0)" ::: "memory");
    __builtin_amdgcn_sched_barrier(0);
    bf16x8 pa = *(const bf16x8*)&Pl[w][lr * 40 + lk * 8];
#pragma unroll
    for (int nf = 0; nf < 8; ++nf) {
      const int d = nf * 16 + lr;
      const int cc = lk ^ ((d >> 1) & 3);
      bf16x8 vfv = *(const bf16x8*)&Vl[cur][d * 32 + cc * 8];
      oacc[nf] = __builtin_amdgcn_mfma_f32_16x16x32_bf16(pa, vfv, oacc[nf], 0, 0, 0);
    }
    asm volatile("s_waitcnt vmcnt(0)" ::: "memory");
    __builtin_amdgcn_s_barrier();
    cur ^= 1;
  }
#undef STG
#pragma unroll
  for (int j2 = 0; j2 < 4; ++j2) {
    float d = den[j2];
    d += __shfl_xor(d, 1); d += __shfl_xor(d, 2); d += __shfl_xor(d, 4); d += __shfl_xor(d, 8);
    den[j2] = 1.0f / fmaxf(d, 1e-20f);
  }
#pragma unroll
  for (int nf = 0; nf < 8; ++nf)
#pragma unroll
    for (int j2 = 0; j2 < 4; ++j2) {
      const int s = srow + lk * 4 + j2;
      const int dd = nf * 16 + lr;
      ctx[((size_t)s * B_ + b) * H_ + h * D_ + dd] = f2b(oacc[nf][j2] * den[j2]);
    }
}

// ------------------------------------------------------------------- host
extern "C" void kernel_launch(void* const* d_in, const int* in_sizes, int n_in,
                              void* d_out, int out_size, void* d_ws, size_t ws_size,
                              hipStream_t stream) {
  (void)in_sizes; (void)n_in; (void)out_size; (void)ws_size;
  char* ws = (char*)d_ws;
  u16* WT     = (u16*)(ws + 0);
  void* MID   = (void*)(ws + 33554432);
  float* XF   = (float*)(ws + 100663296);
  u16* HB     = (u16*)(ws + 134217728);
  u16* MEMB   = (u16*)(ws + 150994944);
  u16* QB     = (u16*)(ws + 167772160);
  u16* KB     = (u16*)(ws + 184549376);
  u16* VTB    = (u16*)(ws + 201326592);
  u64* BMB    = (u64*)(ws + 218103808);
  float* SM   = (float*)(ws + 234881024);
  int* FLAGS  = (int*)(ws + 235044864);

  float* Bias1  = SM + 0;
  float* Bias1o = SM + 8192;
  float* BiasQ  = SM + 10240;
  float* BiasKV = SM + 12288;
  float* BiasD  = SM + 16384;
  float* Bias2  = SM + 18432;
  float* Bias2o = SM + 26624;
  float* G1v = SM + 28672; float* B1v = SM + 30720;
  float* G2v = SM + 32768; float* B2v = SM + 34816;
  float* G3v = SM + 36864; float* B3v = SM + 38912;

  detect_kinds<<<1, 64, 0, stream>>>((const u32*)d_in[0], (const u32*)d_in[2], FLAGS);

  cvt_all<<<160, 256, 0, stream>>>(d_in[10], d_in[12], d_in[14], d_in[16], d_in[18],
                                   d_in[20], d_in[22], d_in[3], d_in[4], d_in[5],
                                   d_in[6], d_in[7], d_in[8], FLAGS, SM);

  mask_bits<<<(B_ * S_ * M_) / 256, 256, 0, stream>>>(d_in[2], FLAGS, BMB);
  cast_in_bf16<<<(MB_ * H_ / 8) / 256, 256, 0, stream>>>(d_in[1], FLAGS, MEMB, MB_ * H_ / 8);

  dim3 blk(256);
  dim3 blk5(512);
  // ---- mlp1  (A/B: gemmk32 on the GELU GEMM)
  layernorm_k<1><<<SB_, blk, 0, stream>>>(d_in[0], FLAGS, G1v, B1v, HB);
  transpose_cast<<<dim3(FF_ / 64, H_ / 64), blk, 0, stream>>>(d_in[9], FLAGS, WT, H_, FF_);
  gemmk32<1, 1><<<dim3(FF_ / 128, SB_ / 128), blk5, 0, stream>>>(HB, WT, Bias1, (u16*)MID, FF_, H_);
  transpose_cast<<<dim3(H_ / 64, FF_ / 64), blk, 0, stream>>>(d_in[11], FLAGS, WT, FF_, H_);
  gemmra512<0, 0, 1, 0, 0, 0><<<dim3(H_ / 128, SB_ / 128), blk5, 0, stream>>>((u16*)MID, WT, Bias1o, nullptr, XF, nullptr, FLAGS, SB_, H_, FF_);

  // ---- memory attention
  layernorm_k<0><<<SB_, blk, 0, stream>>>(XF, FLAGS, G2v, B2v, HB);
  transpose_cast<<<dim3(H_ / 64, H_ / 64), blk, 0, stream>>>(d_in[13], FLAGS, WT, H_, H_);
  gemmra512<0, 0, 0, 0, 0, 1><<<dim3(H_ / 128, SB_ / 128), blk5, 0, stream>>>(HB, WT, BiasQ, nullptr, nullptr, QB, FLAGS, SB_, H_, H_);
  transpose_cast<<<dim3(2 * H_ / 64, H_ / 64), blk, 0, stream>>>(d_in[15], FLAGS, WT, H_, 2 * H_);
  gemmra512<0, 0, 0, 0, 0, 2><<<dim3(2 * H_ / 128, MB_ / 128), blk5, 0, stream>>>(MEMB, WT, BiasKV, nullptr, VTB, KB, FLAGS, MB_, 2 * H_, H_);
  attn_k<<<1024, blk, 0, stream>>>(QB, KB, VTB, (const u32*)BMB, MEMB);
  transpose_cast<<<dim3(H_ / 64, H_ / 64), blk, 0, stream>>>(d_in[17], FLAGS, WT, H_, H_);
  gemmra512<0, 1, 1, 0, 0, 0><<<dim3(H_ / 128, SB_ / 128), blk5, 0, stream>>>(MEMB, WT, BiasD, XF, XF, nullptr, FLAGS, SB_, H_, H_);

  // ---- mlp2  (A/B: gemmk32 on the GELU GEMM)
  layernorm_k<0><<<SB_, blk, 0, stream>>>(XF, FLAGS, G3v, B3v, HB);
  transpose_cast<<<dim3(FF_ / 64, H_ / 64), blk, 0, stream>>>(d_in[19], FLAGS, WT, H_, FF_);
  gemmk32<1, 1><<<dim3(FF_ / 128, SB_ / 128), blk5, 0, stream>>>(HB, WT, Bias2, (u16*)MID, FF_, H_);
  transpose_cast<<<dim3(H_ / 64, FF_ / 64), blk, 0, stream>>>(d_in[21], FLAGS, WT, FF_, H_);
  gemmra512<0, 1, 1, 0, 1, 0><<<dim3(H_ / 128, SB_ / 128), blk5, 0, stream>>>((u16*)MID, WT, Bias2o, XF, d_out, nullptr, FLAGS, SB_, H_, FF_);
}

// Round 17
// 1092.411 us; speedup vs baseline: 1.0419x; 1.0419x over previous
//
#include <hip/hip_runtime.h>
#include <stdint.h>
#include <stddef.h>

typedef __attribute__((ext_vector_type(8))) short bf16x8;
typedef __attribute__((ext_vector_type(4))) float f32x4;
typedef unsigned short u16;
typedef unsigned int u32;
typedef unsigned long long u64;

static constexpr int S_ = 2048, B_ = 2, H_ = 2048, NH_ = 16, D_ = 128, M_ = 2048, FF_ = 8192;
static constexpr int SB_ = S_ * B_;
static constexpr int MB_ = M_ * B_;

__device__ __forceinline__ float b2f(u16 b) {
  union { u32 u; float f; } v; v.u = ((u32)b) << 16; return v.f;
}
__device__ __forceinline__ u16 f2b(float f) {
  union { float f; u32 u; } v; v.f = f;
  u32 u = v.u;
  return (u16)((u + 0x7FFFu + ((u >> 16) & 1u)) >> 16);
}
__device__ __forceinline__ float geluf(float x) {
  float x3 = x * x * x;
  return 0.5f * x * (1.0f + tanhf(0.7978845608028654f * (x + 0.044715f * x3)));
}

#define LDSP(p) (reinterpret_cast<__attribute__((address_space(3))) uint32_t*>(reinterpret_cast<uintptr_t>(p)))
#define GLBP(p) (reinterpret_cast<const __attribute__((address_space(1))) uint32_t*>(reinterpret_cast<uintptr_t>(p)))

// ---------------------------------------------------------------- detectors
__global__ void detect_kinds(const u32* __restrict__ x0, const u32* __restrict__ mask, int* __restrict__ flags) {
  if (threadIdx.x == 0 && blockIdx.x == 0) {
    int cnt = 0;
    for (int i = 0; i < 256; ++i) {
      u32 e = (x0[i] >> 7) & 0xFFu;
      if (e >= 118u && e <= 130u) ++cnt;
    }
    flags[0] = (cnt >= 128) ? 0 : 1;
    int all01 = 1, allf = 1, allb = 1;
    for (int i = 0; i < 256; ++i) {
      u32 v = mask[i];
      if (v > 1u) all01 = 0;
      if (v != 0u && v != 0x3F800000u) allf = 0;
      u32 lo = v & 0xFFFFu, hi = v >> 16;
      if ((lo != 0u && lo != 0x3F80u) || (hi != 0u && hi != 0x3F80u)) allb = 0;
    }
    flags[1] = all01 ? 1 : (allf ? 3 : (allb ? 2 : 0));
  }
}

// mask -> packed bitmask: bit m = 1 iff UNMASKED
__global__ void mask_bits(const void* __restrict__ mraw, const int* __restrict__ flags, u64* __restrict__ bm) {
  int i = blockIdx.x * 256 + threadIdx.x;
  int kind = flags[1];
  int masked;
  if (kind == 1)      masked = ((const int*)mraw)[i] != 0;
  else if (kind == 3) masked = ((const float*)mraw)[i] != 0.0f;
  else if (kind == 2) masked = ((const u16*)mraw)[i] != 0;
  else                masked = ((const unsigned char*)mraw)[i] != 0;
  u64 vote = __ballot(masked == 0);
  if ((threadIdx.x & 63) == 0) bm[i >> 6] = vote;
}

// one launch for all 13 small f32 param conversions
__global__ void cvt_all(const void* s0, const void* s1, const void* s2, const void* s3,
                        const void* s4, const void* s5, const void* s6, const void* s7,
                        const void* s8, const void* s9, const void* s10, const void* s11,
                        const void* s12, const int* __restrict__ flags, float* __restrict__ SM) {
  const int i = blockIdx.x * 256 + threadIdx.x;
  if (i >= 40960) return;
  const void* src; int off;
  if (i < 8192)       { src = s0;  off = 0; }
  else if (i < 10240) { src = s1;  off = 8192; }
  else if (i < 12288) { src = s2;  off = 10240; }
  else if (i < 16384) { src = s3;  off = 12288; }
  else if (i < 18432) { src = s4;  off = 16384; }
  else if (i < 26624) { src = s5;  off = 18432; }
  else if (i < 28672) { src = s6;  off = 26624; }
  else if (i < 30720) { src = s7;  off = 28672; }
  else if (i < 32768) { src = s8;  off = 30720; }
  else if (i < 34816) { src = s9;  off = 32768; }
  else if (i < 36864) { src = s10; off = 34816; }
  else if (i < 38912) { src = s11; off = 36864; }
  else                { src = s12; off = 38912; }
  const int j = i - off;
  SM[i] = flags[0] ? ((const float*)src)[j] : b2f(((const u16*)src)[j]);
}

__global__ void cast_in_bf16(const void* __restrict__ src, const int* __restrict__ flags, u16* __restrict__ dst, int n8) {
  int i = blockIdx.x * 256 + threadIdx.x;
  if (i >= n8) return;
  if (flags[0]) {
    const float4* p = (const float4*)src;
    float4 a = p[i * 2], c = p[i * 2 + 1];
    bf16x8 o;
    o[0] = (short)f2b(a.x); o[1] = (short)f2b(a.y); o[2] = (short)f2b(a.z); o[3] = (short)f2b(a.w);
    o[4] = (short)f2b(c.x); o[5] = (short)f2b(c.y); o[6] = (short)f2b(c.z); o[7] = (short)f2b(c.w);
    *(bf16x8*)&dst[i * 8] = o;
  } else {
    *(bf16x8*)&dst[i * 8] = ((const bf16x8*)src)[i];
  }
}

// ------------------------------------------------------------ transpose+cast
// in [R][C] -> out [C][R] bf16.  Write phase vectorized: each thread packs
// 8 LDS values -> one 16B store (16B/lane, G13) instead of 1 u16/store.
__global__ __launch_bounds__(256) void transpose_cast(const void* __restrict__ in, const int* __restrict__ flags,
                                                      u16* __restrict__ out, int R, int C) {
  __shared__ u16 tile[64][65];
  const int isf = flags[0];
  const int tr = blockIdx.y * 64, tc = blockIdx.x * 64;
  const int tx = threadIdx.x & 63, ty = threadIdx.x >> 6;
  const float* inf = (const float*)in;
  const u16* inb = (const u16*)in;
#pragma unroll
  for (int i = 0; i < 16; ++i) {
    int r = ty * 16 + i;
    size_t idx = (size_t)(tr + r) * C + tc + tx;
    tile[r][tx] = isf ? f2b(inf[idx]) : inb[idx];
  }
  __syncthreads();
  // write: thread t -> col c = t>>2 (0..63), row-block rb = t&3 (16 rows), 2x bf16x8
  const int c = threadIdx.x >> 2, rb = threadIdx.x & 3;
#pragma unroll
  for (int i2 = 0; i2 < 2; ++i2) {
    bf16x8 o;
#pragma unroll
    for (int i = 0; i < 8; ++i) o[i] = (short)tile[rb * 16 + i2 * 8 + i][c];
    *(bf16x8*)&out[(size_t)(tc + c) * R + tr + rb * 16 + i2 * 8] = o;
  }
}

// ---------------------------------------------------------------- layernorm
template <int EXT>
__global__ __launch_bounds__(256) void layernorm_k(const void* __restrict__ xin, const int* __restrict__ flags,
                                                   const float* __restrict__ g, const float* __restrict__ bta,
                                                   u16* __restrict__ out) {
  const int row = blockIdx.x, t = threadIdx.x;
  float v[8];
  bool bfmode = EXT && (flags[0] == 0);
  if (bfmode) {
    const u16* xr = (const u16*)xin + (size_t)row * H_ + t * 8;
    bf16x8 a = *(const bf16x8*)xr;
#pragma unroll
    for (int j = 0; j < 8; ++j) v[j] = b2f((u16)a[j]);
  } else {
    const float* xr = (const float*)xin + (size_t)row * H_ + t * 8;
    float4 a = *(const float4*)xr, c = *(const float4*)(xr + 4);
    v[0] = a.x; v[1] = a.y; v[2] = a.z; v[3] = a.w;
    v[4] = c.x; v[5] = c.y; v[6] = c.z; v[7] = c.w;
  }
  float s1 = 0.f, s2 = 0.f;
#pragma unroll
  for (int j = 0; j < 8; ++j) { s1 += v[j]; s2 += v[j] * v[j]; }
#pragma unroll
  for (int off = 32; off > 0; off >>= 1) { s1 += __shfl_down(s1, off); s2 += __shfl_down(s2, off); }
  __shared__ float red[8];
  const int w = t >> 6;
  if ((t & 63) == 0) { red[w] = s1; red[4 + w] = s2; }
  __syncthreads();
  s1 = red[0] + red[1] + red[2] + red[3];
  s2 = red[4] + red[5] + red[6] + red[7];
  const float mean = s1 * (1.0f / H_);
  const float rstd = rsqrtf(s2 * (1.0f / H_) - mean * mean + 1e-5f);
  bf16x8 o;
#pragma unroll
  for (int j = 0; j < 8; ++j) {
    float y = (v[j] - mean) * rstd * g[t * 8 + j] + bta[t * 8 + j];
    o[j] = (short)f2b(y);
  }
  *(bf16x8*)(out + (size_t)row * H_ + t * 8) = o;
}

// ------------------------------------------------------------------- GEMM
// gemmra512 (round-13 winner) + fused l2-norm epilogues (round-15).
// 128x128 tile, 512 thr = 8 waves (2M x 4N, 64x32/wave), BK=64, 2-slot
// double buffer (64KB -> 2 blocks/CU = 4 waves/SIMD), register read-ahead,
// ONE barrier + one vmcnt(0) per slice, 16x16x32 MFMA.
template <int GELU, int RES, int WF, int WB, int ODYN, int EPI>
__global__ __launch_bounds__(512, 2) void gemmra512(const u16* __restrict__ A, const u16* __restrict__ Bt,
                                                    const float* __restrict__ bias, const float* __restrict__ res,
                                                    void* __restrict__ outF, u16* __restrict__ outB,
                                                    const int* __restrict__ flags, int Mr, int N, int K) {
  __shared__ u16 lds[32768];   // 64 KiB
  const int t = threadIdx.x;
  const int w = t >> 6, l = t & 63, lr = l & 15, lk = l >> 4;
  const int wr = w >> 2, wc = w & 3;
  const int gx = gridDim.x, gy = gridDim.y;
  const int orig = blockIdx.y * gx + blockIdx.x;
  const int nwg = gx * gy, per = nwg >> 3;
  int tm, tn;
  if ((gx & 7) == 0 && (per & 7) == 0) {
    const int xcd = orig & 7, p = orig >> 3;
    const int ncx = gx >> 3, cy = per >> 3;
    const int ccol = xcd % ncx, crow = xcd / ncx;
    const int px = p & 7, py = p >> 3;
    tn = (ccol * 8 + px) * 128;
    tm = (crow * cy + py) * 128;
  } else {
    tn = (orig % gx) * 128;
    tm = (orig / gx) * 128;
  }
  u32 aofs[2], bofs[2];
#pragma unroll
  for (int i = 0; i < 2; ++i) {
    const int idx = i * 512 + t;
    const int srow = idx >> 3, sc = idx & 7;
    const int lc = sc ^ (srow & 7);
    aofs[i] = (u32)(tm + srow) * (u32)K + (u32)lc * 8;
    bofs[i] = (u32)(tn + srow) * (u32)K + (u32)lc * 8;
  }
  const int wdst = w * 512;
  const int cso0 = ((0 + lk) ^ (lr & 7)) * 8;
  const int cso1 = ((4 + lk) ^ (lr & 7)) * 8;
  int arow[4], brow[2];
#pragma unroll
  for (int f = 0; f < 4; ++f) arow[f] = (wr * 64 + f * 16 + lr) * 64;
#pragma unroll
  for (int f = 0; f < 2; ++f) brow[f] = (wc * 32 + f * 16 + lr) * 64;

  const int NS = K >> 6;
  f32x4 acc[4][2] = {};

#define STG(sl) do {                                                                                  \
    u16* Ad = lds + ((sl) & 1) * 16384;                                                               \
    u16* Bd = Ad + 8192;                                                                              \
    const u32 ko = (u32)(sl) * 64;                                                                    \
    _Pragma("unroll")                                                                                 \
    for (int i = 0; i < 2; ++i) {                                                                     \
      __builtin_amdgcn_global_load_lds(GLBP(A + aofs[i] + ko), LDSP(Ad + i * 4096 + wdst), 16, 0, 0); \
      __builtin_amdgcn_global_load_lds(GLBP(Bt + bofs[i] + ko), LDSP(Bd + i * 4096 + wdst), 16, 0, 0);\
    }                                                                                                 \
  } while (0)
#define RD(afX, bqX, sl, cso) do {                                                                    \
    const u16* As_ = lds + ((sl) & 1) * 16384;                                                        \
    const u16* Bs_ = As_ + 8192;                                                                      \
    _Pragma("unroll")                                                                                 \
    for (int f = 0; f < 4; ++f) afX[f] = *(const bf16x8*)(As_ + arow[f] + (cso));                     \
    _Pragma("unroll")                                                                                 \
    for (int f = 0; f < 2; ++f) bqX[f] = *(const bf16x8*)(Bs_ + brow[f] + (cso));                     \
  } while (0)
#define MM(afX, bqX)                                                                                  \
  _Pragma("unroll") for (int nf = 0; nf < 2; ++nf)                                                    \
  _Pragma("unroll") for (int mf = 0; mf < 4; ++mf)                                                    \
    acc[mf][nf] = __builtin_amdgcn_mfma_f32_16x16x32_bf16(afX[mf], bqX[nf], acc[mf][nf], 0, 0, 0);

  bf16x8 afA[4], bqA[2], afB[4], bqB[2];

  STG(0);
  asm volatile("s_waitcnt vmcnt(0)" ::: "memory");
  __builtin_amdgcn_s_barrier();
  RD(afA, bqA, 0, cso0);
  asm volatile("s_waitcnt lgkmcnt(0)" ::: "memory");
  __builtin_amdgcn_sched_barrier(0);

  for (int s = 0; s < NS; ++s) {
    if (s + 1 < NS) STG(s + 1);
    RD(afB, bqB, s, cso1);
    __builtin_amdgcn_sched_barrier(0);
    __builtin_amdgcn_s_setprio(1);
    MM(afA, bqA);
    __builtin_amdgcn_s_setprio(0);
    asm volatile("s_waitcnt lgkmcnt(0)" ::: "memory");
    __builtin_amdgcn_sched_barrier(0);
    asm volatile("s_waitcnt vmcnt(0)" ::: "memory");
    __builtin_amdgcn_s_barrier();
    if (s + 1 < NS) RD(afA, bqA, s + 1, cso0);
    __builtin_amdgcn_sched_barrier(0);
    __builtin_amdgcn_s_setprio(1);
    MM(afB, bqB);
    __builtin_amdgcn_s_setprio(0);
    asm volatile("s_waitcnt lgkmcnt(0)" ::: "memory");
    __builtin_amdgcn_sched_barrier(0);
  }
#undef STG
#undef RD
#undef MM

  (void)Mr;
  if constexpr (EPI == 0) {
    const int obf = ODYN ? (flags[0] ? 0 : 1) : 0;
#pragma unroll
    for (int mf = 0; mf < 4; ++mf) {
#pragma unroll
      for (int nf = 0; nf < 2; ++nf) {
        const int col = tn + wc * 32 + nf * 16 + lr;
        const float bv = bias[col];
#pragma unroll
        for (int j = 0; j < 4; ++j) {
          const int rw = tm + wr * 64 + mf * 16 + lk * 4 + j;
          float vv = acc[mf][nf][j] + bv;
          if (RES) vv += res[(size_t)rw * N + col];
          if (GELU) vv = geluf(vv);
          if (WF) {
            if (ODYN && obf) ((u16*)outF)[(size_t)rw * N + col] = f2b(vv);
            else ((float*)outF)[(size_t)rw * N + col] = vv;
          }
          if (WB) outB[(size_t)rw * N + col] = f2b(vv);
        }
      }
    }
  } else {
    float* red = reinterpret_cast<float*>(lds);
    u16* vt = lds + 4096;
    float bv2[2];
#pragma unroll
    for (int nf = 0; nf < 2; ++nf) bv2[nf] = bias[tn + wc * 32 + nf * 16 + lr];
    float ss[4][4];
#pragma unroll
    for (int mf = 0; mf < 4; ++mf)
#pragma unroll
      for (int j = 0; j < 4; ++j) {
        float s = 0.f;
#pragma unroll
        for (int nf = 0; nf < 2; ++nf) {
          float v = acc[mf][nf][j] + bv2[nf];
          s += v * v;
        }
        s += __shfl_xor(s, 1); s += __shfl_xor(s, 2); s += __shfl_xor(s, 4); s += __shfl_xor(s, 8);
        ss[mf][j] = s;
      }
    if (lr == 0) {
#pragma unroll
      for (int mf = 0; mf < 4; ++mf)
#pragma unroll
        for (int j = 0; j < 4; ++j) {
          const int row = wr * 64 + mf * 16 + lk * 4 + j;
          red[row * 4 + wc] = ss[mf][j];
        }
    }
    __syncthreads();
    float rs[4][4];
#pragma unroll
    for (int mf = 0; mf < 4; ++mf)
#pragma unroll
      for (int j = 0; j < 4; ++j) {
        const int row = wr * 64 + mf * 16 + lk * 4 + j;
        rs[mf][j] = rsqrtf(red[row * 4 + 0] + red[row * 4 + 1] + red[row * 4 + 2] + red[row * 4 + 3] + 1e-12f);
      }
    if constexpr (EPI == 1) {
      const int h = tn >> 7;
#pragma unroll
      for (int mf = 0; mf < 4; ++mf)
#pragma unroll
        for (int nf = 0; nf < 2; ++nf) {
          const int d = wc * 32 + nf * 16 + lr;
#pragma unroll
          for (int j = 0; j < 4; ++j) {
            const int rw = tm + wr * 64 + mf * 16 + lk * 4 + j;
            const int sR = rw >> 1, bb = rw & 1;
            float v = (acc[mf][nf][j] + bv2[nf]) * rs[mf][j];
            outB[(((size_t)(bb * NH_ + h) * S_) + sR) * D_ + d] = f2b(v);
          }
        }
    } else {
      const int h = tn >> 8;
      const int isV = (tn >> 7) & 1;
      if (!isV) {
#pragma unroll
        for (int mf = 0; mf < 4; ++mf)
#pragma unroll
          for (int nf = 0; nf < 2; ++nf) {
            const int d = wc * 32 + nf * 16 + lr;
#pragma unroll
            for (int j = 0; j < 4; ++j) {
              const int rw = tm + wr * 64 + mf * 16 + lk * 4 + j;
              const int mR = rw >> 1, bb = rw & 1;
              float v = (acc[mf][nf][j] + bv2[nf]) * rs[mf][j];
              outB[(((size_t)(bb * NH_ + h) * M_) + mR) * D_ + d] = f2b(v);
            }
          }
      } else {
#pragma unroll
        for (int mf = 0; mf < 4; ++mf)
#pragma unroll
          for (int nf = 0; nf < 2; ++nf) {
            const int d = wc * 32 + nf * 16 + lr;
#pragma unroll
            for (int j = 0; j < 4; ++j) {
              const int rl = wr * 64 + mf * 16 + lk * 4 + j;
              float v = (acc[mf][nf][j] + bv2[nf]) * rs[mf][j];
              vt[((rl & 1) * 128 + d) * 72 + (rl >> 1)] = f2b(v);
            }
          }
        __syncthreads();
        const int dd = t >> 2, bb = (t >> 1) & 1, half = t & 1;
        const u16* src = vt + ((size_t)(bb * 128 + dd) * 72) + half * 32;
        u16* dst = (u16*)outF + (((size_t)(bb * NH_ + h) * D_ + dd) * M_) + (tm >> 1) + half * 32;
#pragma unroll
        for (int i = 0; i < 4; ++i) *(bf16x8*)&dst[i * 8] = *(const bf16x8*)&src[i * 8];
      }
    }
  }
}

// -------------------------------------------------------------- attention
// unchanged (verified; ~130 us)
__global__ __launch_bounds__(256, 3) void attn_k(const u16* __restrict__ Q, const u16* __restrict__ Kq,
                                                 const u16* __restrict__ Vt, const u32* __restrict__ BM32,
                                                 u16* __restrict__ ctx) {
  __shared__ u16 Kl[2][4096];
  __shared__ u16 Vl[2][4096];
  __shared__ u16 Pl[4][16 * 40];
  const int t = threadIdx.x, w = t >> 6, l = t & 63, lr = l & 15, lk = l >> 4;
  const int lin = blockIdx.x;
  const int xcd = lin & 7, idx = lin >> 3;
  const int bh = xcd * 4 + (idx >> 5);
  const int chunk = idx & 31;
  const int b = bh >> 4, h = bh & 15;
  const int srow = chunk * 64 + w * 16;
  const u16* Qb = Q + ((size_t)bh * S_ + srow) * D_;
  bf16x8 qf[4];
#pragma unroll
  for (int kc = 0; kc < 4; ++kc)
    qf[kc] = *(const bf16x8*)&Qb[lr * D_ + kc * 32 + lk * 8];
  f32x4 oacc[8] = {};
  float den[4] = {};
  const u16* Kb = Kq + (size_t)bh * M_ * D_;
  const u16* Vb = Vt + (size_t)bh * D_ * M_;
  const float invn = 0.08838834764831845f;
  u32 ksrc[2], vsrc[2];
#pragma unroll
  for (int i = 0; i < 2; ++i) {
    const int kidx = i * 256 + t;
    const int kr = kidx >> 4, kc_ = (kidx & 15) ^ (kr & 7);
    ksrc[i] = (u32)kr * D_ + (u32)kc_ * 8;
    const int vidx = i * 256 + t;
    const int vd = vidx >> 2, vc = (vidx & 3) ^ ((vd >> 1) & 3);
    vsrc[i] = (u32)vd * M_ + (u32)vc * 8;
  }
  const int wdst = w * 64 * 8;
  u32 mrow[4];
#pragma unroll
  for (int j2 = 0; j2 < 4; ++j2)
    mrow[j2] = ((u32)b * S_ + (u32)(srow + lk * 4 + j2)) * 64u;

#define STG(buf, m0) do {                                                                              \
    _Pragma("unroll")                                                                                  \
    for (int i = 0; i < 2; ++i) {                                                                      \
      __builtin_amdgcn_global_load_lds(GLBP(Kb + (size_t)(m0) * D_ + ksrc[i]),                         \
                                       LDSP(&Kl[buf][i * 2048 + wdst]), 16, 0, 0);                     \
      __builtin_amdgcn_global_load_lds(GLBP(Vb + (size_t)(m0) + vsrc[i]),                              \
                                       LDSP(&Vl[buf][i * 2048 + wdst]), 16, 0, 0);                     \
    }                                                                                                  \
  } while (0)

  STG(0, 0);
  asm volatile("s_waitcnt vmcnt(0)" ::: "memory");
  __builtin_amdgcn_s_barrier();
  int cur = 0;

  for (int t64 = 0; t64 < M_ / 32; ++t64) {
    const int m0 = t64 * 32;
    if (t64 + 1 < M_ / 32) STG(cur ^ 1, m0 + 32);
    u32 mw[4];
#pragma unroll
    for (int j2 = 0; j2 < 4; ++j2) mw[j2] = BM32[mrow[j2] + t64];
    f32x4 sc[2] = {};
#pragma unroll
    for (int mf = 0; mf < 2; ++mf) {
      const int r = mf * 16 + lr;
#pragma unroll
      for (int kc = 0; kc < 4; ++kc) {
        const int cc = ((kc * 4 + lk) ^ (r & 7));
        bf16x8 kfv = *(const bf16x8*)&Kl[cur][r * 128 + cc * 8];
        sc[mf] = __builtin_amdgcn_mfma_f32_16x16x32_bf16(qf[kc], kfv, sc[mf], 0, 0, 0);
      }
    }
#pragma unroll
    for (int j2 = 0; j2 < 4; ++j2) {
      const int rloc = lk * 4 + j2;
#pragma unroll
      for (int mf = 0; mf < 2; ++mf) {
        float p = __expf(sc[mf][j2] * invn);
        p = ((mw[j2] >> (mf * 16 + lr)) & 1u) ? p : 0.0f;
        den[j2] += p;
        Pl[w][rloc * 40 + mf * 16 + lr] = f2b(p);
      }
    }
    asm volatile("s_waitcnt lgkmcnt(0)" ::: "memory");
    __builtin_amdgcn_sched_barrier(0);
    bf16x8 pa = *(const bf16x8*)&Pl[w][lr * 40 + lk * 8];
#pragma unroll
    for (int nf = 0; nf < 8; ++nf) {
      const int d = nf * 16 + lr;
      const int cc = lk ^ ((d >> 1) & 3);
      bf16x8 vfv = *(const bf16x8*)&Vl[cur][d * 32 + cc * 8];
      oacc[nf] = __builtin_amdgcn_mfma_f32_16x16x32_bf16(pa, vfv, oacc[nf], 0, 0, 0);
    }
    asm volatile("s_waitcnt vmcnt(0)" ::: "memory");
    __builtin_amdgcn_s_barrier();
    cur ^= 1;
  }
#undef STG
#pragma unroll
  for (int j2 = 0; j2 < 4; ++j2) {
    float d = den[j2];
    d += __shfl_xor(d, 1); d += __shfl_xor(d, 2); d += __shfl_xor(d, 4); d += __shfl_xor(d, 8);
    den[j2] = 1.0f / fmaxf(d, 1e-20f);
  }
#pragma unroll
  for (int nf = 0; nf < 8; ++nf)
#pragma unroll
    for (int j2 = 0; j2 < 4; ++j2) {
      const int s = srow + lk * 4 + j2;
      const int dd = nf * 16 + lr;
      ctx[((size_t)s * B_ + b) * H_ + h * D_ + dd] = f2b(oacc[nf][j2] * den[j2]);
    }
}

// ------------------------------------------------------------------- host
extern "C" void kernel_launch(void* const* d_in, const int* in_sizes, int n_in,
                              void* d_out, int out_size, void* d_ws, size_t ws_size,
                              hipStream_t stream) {
  (void)in_sizes; (void)n_in; (void)out_size; (void)ws_size;
  char* ws = (char*)d_ws;
  u16* WT     = (u16*)(ws + 0);
  void* MID   = (void*)(ws + 33554432);
  float* XF   = (float*)(ws + 100663296);
  u16* HB     = (u16*)(ws + 134217728);
  u16* MEMB   = (u16*)(ws + 150994944);
  u16* QB     = (u16*)(ws + 167772160);
  u16* KB     = (u16*)(ws + 184549376);
  u16* VTB    = (u16*)(ws + 201326592);
  u64* BMB    = (u64*)(ws + 218103808);
  float* SM   = (float*)(ws + 234881024);
  int* FLAGS  = (int*)(ws + 235044864);

  float* Bias1  = SM + 0;
  float* Bias1o = SM + 8192;
  float* BiasQ  = SM + 10240;
  float* BiasKV = SM + 12288;
  float* BiasD  = SM + 16384;
  float* Bias2  = SM + 18432;
  float* Bias2o = SM + 26624;
  float* G1v = SM + 28672; float* B1v = SM + 30720;
  float* G2v = SM + 32768; float* B2v = SM + 34816;
  float* G3v = SM + 36864; float* B3v = SM + 38912;

  detect_kinds<<<1, 64, 0, stream>>>((const u32*)d_in[0], (const u32*)d_in[2], FLAGS);

  cvt_all<<<160, 256, 0, stream>>>(d_in[10], d_in[12], d_in[14], d_in[16], d_in[18],
                                   d_in[20], d_in[22], d_in[3], d_in[4], d_in[5],
                                   d_in[6], d_in[7], d_in[8], FLAGS, SM);

  mask_bits<<<(B_ * S_ * M_) / 256, 256, 0, stream>>>(d_in[2], FLAGS, BMB);
  cast_in_bf16<<<(MB_ * H_ / 8) / 256, 256, 0, stream>>>(d_in[1], FLAGS, MEMB, MB_ * H_ / 8);

  dim3 blk(256);
  dim3 blk5(512);
  // ---- mlp1
  layernorm_k<1><<<SB_, blk, 0, stream>>>(d_in[0], FLAGS, G1v, B1v, HB);
  transpose_cast<<<dim3(FF_ / 64, H_ / 64), blk, 0, stream>>>(d_in[9], FLAGS, WT, H_, FF_);
  gemmra512<1, 0, 0, 1, 0, 0><<<dim3(FF_ / 128, SB_ / 128), blk5, 0, stream>>>(HB, WT, Bias1, nullptr, nullptr, (u16*)MID, FLAGS, SB_, FF_, H_);
  transpose_cast<<<dim3(H_ / 64, FF_ / 64), blk, 0, stream>>>(d_in[11], FLAGS, WT, FF_, H_);
  gemmra512<0, 0, 1, 0, 0, 0><<<dim3(H_ / 128, SB_ / 128), blk5, 0, stream>>>((u16*)MID, WT, Bias1o, nullptr, XF, nullptr, FLAGS, SB_, H_, FF_);

  // ---- memory attention
  layernorm_k<0><<<SB_, blk, 0, stream>>>(XF, FLAGS, G2v, B2v, HB);
  transpose_cast<<<dim3(H_ / 64, H_ / 64), blk, 0, stream>>>(d_in[13], FLAGS, WT, H_, H_);
  gemmra512<0, 0, 0, 0, 0, 1><<<dim3(H_ / 128, SB_ / 128), blk5, 0, stream>>>(HB, WT, BiasQ, nullptr, nullptr, QB, FLAGS, SB_, H_, H_);
  transpose_cast<<<dim3(2 * H_ / 64, H_ / 64), blk, 0, stream>>>(d_in[15], FLAGS, WT, H_, 2 * H_);
  gemmra512<0, 0, 0, 0, 0, 2><<<dim3(2 * H_ / 128, MB_ / 128), blk5, 0, stream>>>(MEMB, WT, BiasKV, nullptr, VTB, KB, FLAGS, MB_, 2 * H_, H_);
  attn_k<<<1024, blk, 0, stream>>>(QB, KB, VTB, (const u32*)BMB, MEMB);
  transpose_cast<<<dim3(H_ / 64, H_ / 64), blk, 0, stream>>>(d_in[17], FLAGS, WT, H_, H_);
  gemmra512<0, 1, 1, 0, 0, 0><<<dim3(H_ / 128, SB_ / 128), blk5, 0, stream>>>(MEMB, WT, BiasD, XF, XF, nullptr, FLAGS, SB_, H_, H_);

  // ---- mlp2
  layernorm_k<0><<<SB_, blk, 0, stream>>>(XF, FLAGS, G3v, B3v, HB);
  transpose_cast<<<dim3(FF_ / 64, H_ / 64), blk, 0, stream>>>(d_in[19], FLAGS, WT, H_, FF_);
  gemmra512<1, 0, 0, 1, 0, 0><<<dim3(FF_ / 128, SB_ / 128), blk5, 0, stream>>>(HB, WT, Bias2, nullptr, nullptr, (u16*)MID, FLAGS, SB_, FF_, H_);
  transpose_cast<<<dim3(H_ / 64, FF_ / 64), blk, 0, stream>>>(d_in[21], FLAGS, WT, FF_, H_);
  gemmra512<0, 1, 1, 0, 1, 0><<<dim3(H_ / 128, SB_ / 128), blk5, 0, stream>>>((u16*)MID, WT, Bias2o, XF, d_out, nullptr, FLAGS, SB_, H_, FF_);
}

// Round 18
// 1091.206 us; speedup vs baseline: 1.0430x; 1.0011x over previous
//
#include <hip/hip_runtime.h>
#include <stdint.h>
#include <stddef.h>

typedef __attribute__((ext_vector_type(8))) short bf16x8;
typedef __attribute__((ext_vector_type(4))) float f32x4;
typedef unsigned short u16;
typedef unsigned int u32;
typedef unsigned long long u64;

static constexpr int S_ = 2048, B_ = 2, H_ = 2048, NH_ = 16, D_ = 128, M_ = 2048, FF_ = 8192;
static constexpr int SB_ = S_ * B_;
static constexpr int MB_ = M_ * B_;

__device__ __forceinline__ float b2f(u16 b) {
  union { u32 u; float f; } v; v.u = ((u32)b) << 16; return v.f;
}
__device__ __forceinline__ u16 f2b(float f) {
  union { float f; u32 u; } v; v.f = f;
  u32 u = v.u;
  return (u16)((u + 0x7FFFu + ((u >> 16) & 1u)) >> 16);
}
__device__ __forceinline__ float geluf(float x) {
  float x3 = x * x * x;
  return 0.5f * x * (1.0f + tanhf(0.7978845608028654f * (x + 0.044715f * x3)));
}

#define LDSP(p) (reinterpret_cast<__attribute__((address_space(3))) uint32_t*>(reinterpret_cast<uintptr_t>(p)))
#define GLBP(p) (reinterpret_cast<const __attribute__((address_space(1))) uint32_t*>(reinterpret_cast<uintptr_t>(p)))

// ---------------------------------------------------------------- detectors
__global__ void detect_kinds(const u32* __restrict__ x0, const u32* __restrict__ mask, int* __restrict__ flags) {
  if (threadIdx.x == 0 && blockIdx.x == 0) {
    int cnt = 0;
    for (int i = 0; i < 256; ++i) {
      u32 e = (x0[i] >> 7) & 0xFFu;
      if (e >= 118u && e <= 130u) ++cnt;
    }
    flags[0] = (cnt >= 128) ? 0 : 1;
    int all01 = 1, allf = 1, allb = 1;
    for (int i = 0; i < 256; ++i) {
      u32 v = mask[i];
      if (v > 1u) all01 = 0;
      if (v != 0u && v != 0x3F800000u) allf = 0;
      u32 lo = v & 0xFFFFu, hi = v >> 16;
      if ((lo != 0u && lo != 0x3F80u) || (hi != 0u && hi != 0x3F80u)) allb = 0;
    }
    flags[1] = all01 ? 1 : (allf ? 3 : (allb ? 2 : 0));
  }
}

// fused: [0,16384) blocks -> mask bitmask; [16384,20480) -> mem bf16 cast
__global__ void prep_k(const void* __restrict__ mraw, const void* __restrict__ mem,
                       const int* __restrict__ flags, u64* __restrict__ bm, u16* __restrict__ dst) {
  const int bid = blockIdx.x;
  if (bid < 16384) {
    const int i = bid * 256 + threadIdx.x;
    const int kind = flags[1];
    int masked;
    if (kind == 1)      masked = ((const int*)mraw)[i] != 0;
    else if (kind == 3) masked = ((const float*)mraw)[i] != 0.0f;
    else if (kind == 2) masked = ((const u16*)mraw)[i] != 0;
    else                masked = ((const unsigned char*)mraw)[i] != 0;
    u64 vote = __ballot(masked == 0);
    if ((threadIdx.x & 63) == 0) bm[i >> 6] = vote;
  } else {
    const int i = (bid - 16384) * 256 + threadIdx.x;   // i < MB_*H_/8 = 1048576
    if (flags[0]) {
      const float4* p = (const float4*)mem;
      float4 a = p[i * 2], c = p[i * 2 + 1];
      bf16x8 o;
      o[0] = (short)f2b(a.x); o[1] = (short)f2b(a.y); o[2] = (short)f2b(a.z); o[3] = (short)f2b(a.w);
      o[4] = (short)f2b(c.x); o[5] = (short)f2b(c.y); o[6] = (short)f2b(c.z); o[7] = (short)f2b(c.w);
      *(bf16x8*)&dst[i * 8] = o;
    } else {
      *(bf16x8*)&dst[i * 8] = ((const bf16x8*)mem)[i];
    }
  }
}

// one launch for all 13 small f32 param conversions
__global__ void cvt_all(const void* s0, const void* s1, const void* s2, const void* s3,
                        const void* s4, const void* s5, const void* s6, const void* s7,
                        const void* s8, const void* s9, const void* s10, const void* s11,
                        const void* s12, const int* __restrict__ flags, float* __restrict__ SM) {
  const int i = blockIdx.x * 256 + threadIdx.x;
  if (i >= 40960) return;
  const void* src; int off;
  if (i < 8192)       { src = s0;  off = 0; }
  else if (i < 10240) { src = s1;  off = 8192; }
  else if (i < 12288) { src = s2;  off = 10240; }
  else if (i < 16384) { src = s3;  off = 12288; }
  else if (i < 18432) { src = s4;  off = 16384; }
  else if (i < 26624) { src = s5;  off = 18432; }
  else if (i < 28672) { src = s6;  off = 26624; }
  else if (i < 30720) { src = s7;  off = 28672; }
  else if (i < 32768) { src = s8;  off = 30720; }
  else if (i < 34816) { src = s9;  off = 32768; }
  else if (i < 36864) { src = s10; off = 34816; }
  else if (i < 38912) { src = s11; off = 36864; }
  else                { src = s12; off = 38912; }
  const int j = i - off;
  SM[i] = flags[0] ? ((const float*)src)[j] : b2f(((const u16*)src)[j]);
}

// ------------------------------------------------------------ transpose+cast
__global__ __launch_bounds__(256) void transpose_cast(const void* __restrict__ in, const int* __restrict__ flags,
                                                      u16* __restrict__ out, int R, int C) {
  __shared__ u16 tile[64][65];
  const int isf = flags[0];
  const int tr = blockIdx.y * 64, tc = blockIdx.x * 64;
  const int tx = threadIdx.x & 63, ty = threadIdx.x >> 6;
  const float* inf = (const float*)in;
  const u16* inb = (const u16*)in;
#pragma unroll
  for (int i = 0; i < 16; ++i) {
    int r = ty * 16 + i;
    size_t idx = (size_t)(tr + r) * C + tc + tx;
    tile[r][tx] = isf ? f2b(inf[idx]) : inb[idx];
  }
  __syncthreads();
  const int c = threadIdx.x >> 2, rb = threadIdx.x & 3;
#pragma unroll
  for (int i2 = 0; i2 < 2; ++i2) {
    bf16x8 o;
#pragma unroll
    for (int i = 0; i < 8; ++i) o[i] = (short)tile[rb * 16 + i2 * 8 + i][c];
    *(bf16x8*)&out[(size_t)(tc + c) * R + tr + rb * 16 + i2 * 8] = o;
  }
}

// ---------------------------------------------------------------- layernorm
template <int EXT>
__global__ __launch_bounds__(256) void layernorm_k(const void* __restrict__ xin, const int* __restrict__ flags,
                                                   const float* __restrict__ g, const float* __restrict__ bta,
                                                   u16* __restrict__ out) {
  const int row = blockIdx.x, t = threadIdx.x;
  float v[8];
  bool bfmode = EXT && (flags[0] == 0);
  if (bfmode) {
    const u16* xr = (const u16*)xin + (size_t)row * H_ + t * 8;
    bf16x8 a = *(const bf16x8*)xr;
#pragma unroll
    for (int j = 0; j < 8; ++j) v[j] = b2f((u16)a[j]);
  } else {
    const float* xr = (const float*)xin + (size_t)row * H_ + t * 8;
    float4 a = *(const float4*)xr, c = *(const float4*)(xr + 4);
    v[0] = a.x; v[1] = a.y; v[2] = a.z; v[3] = a.w;
    v[4] = c.x; v[5] = c.y; v[6] = c.z; v[7] = c.w;
  }
  float s1 = 0.f, s2 = 0.f;
#pragma unroll
  for (int j = 0; j < 8; ++j) { s1 += v[j]; s2 += v[j] * v[j]; }
#pragma unroll
  for (int off = 32; off > 0; off >>= 1) { s1 += __shfl_down(s1, off); s2 += __shfl_down(s2, off); }
  __shared__ float red[8];
  const int w = t >> 6;
  if ((t & 63) == 0) { red[w] = s1; red[4 + w] = s2; }
  __syncthreads();
  s1 = red[0] + red[1] + red[2] + red[3];
  s2 = red[4] + red[5] + red[6] + red[7];
  const float mean = s1 * (1.0f / H_);
  const float rstd = rsqrtf(s2 * (1.0f / H_) - mean * mean + 1e-5f);
  bf16x8 o;
#pragma unroll
  for (int j = 0; j < 8; ++j) {
    float y = (v[j] - mean) * rstd * g[t * 8 + j] + bta[t * 8 + j];
    o[j] = (short)f2b(y);
  }
  *(bf16x8*)(out + (size_t)row * H_ + t * 8) = o;
}

// ------------------------------------------------------------------- GEMM
// gemmra512 (round-13 winner) + fused l2-norm epilogues (round-15).
template <int GELU, int RES, int WF, int WB, int ODYN, int EPI>
__global__ __launch_bounds__(512, 2) void gemmra512(const u16* __restrict__ A, const u16* __restrict__ Bt,
                                                    const float* __restrict__ bias, const float* __restrict__ res,
                                                    void* __restrict__ outF, u16* __restrict__ outB,
                                                    const int* __restrict__ flags, int Mr, int N, int K) {
  __shared__ u16 lds[32768];   // 64 KiB
  const int t = threadIdx.x;
  const int w = t >> 6, l = t & 63, lr = l & 15, lk = l >> 4;
  const int wr = w >> 2, wc = w & 3;
  const int gx = gridDim.x, gy = gridDim.y;
  const int orig = blockIdx.y * gx + blockIdx.x;
  const int nwg = gx * gy, per = nwg >> 3;
  int tm, tn;
  if ((gx & 7) == 0 && (per & 7) == 0) {
    const int xcd = orig & 7, p = orig >> 3;
    const int ncx = gx >> 3, cy = per >> 3;
    const int ccol = xcd % ncx, crow = xcd / ncx;
    const int px = p & 7, py = p >> 3;
    tn = (ccol * 8 + px) * 128;
    tm = (crow * cy + py) * 128;
  } else {
    tn = (orig % gx) * 128;
    tm = (orig / gx) * 128;
  }
  u32 aofs[2], bofs[2];
#pragma unroll
  for (int i = 0; i < 2; ++i) {
    const int idx = i * 512 + t;
    const int srow = idx >> 3, sc = idx & 7;
    const int lc = sc ^ (srow & 7);
    aofs[i] = (u32)(tm + srow) * (u32)K + (u32)lc * 8;
    bofs[i] = (u32)(tn + srow) * (u32)K + (u32)lc * 8;
  }
  const int wdst = w * 512;
  const int cso0 = ((0 + lk) ^ (lr & 7)) * 8;
  const int cso1 = ((4 + lk) ^ (lr & 7)) * 8;
  int arow[4], brow[2];
#pragma unroll
  for (int f = 0; f < 4; ++f) arow[f] = (wr * 64 + f * 16 + lr) * 64;
#pragma unroll
  for (int f = 0; f < 2; ++f) brow[f] = (wc * 32 + f * 16 + lr) * 64;

  const int NS = K >> 6;
  f32x4 acc[4][2] = {};

#define STG(sl) do {                                                                                  \
    u16* Ad = lds + ((sl) & 1) * 16384;                                                               \
    u16* Bd = Ad + 8192;                                                                              \
    const u32 ko = (u32)(sl) * 64;                                                                    \
    _Pragma("unroll")                                                                                 \
    for (int i = 0; i < 2; ++i) {                                                                     \
      __builtin_amdgcn_global_load_lds(GLBP(A + aofs[i] + ko), LDSP(Ad + i * 4096 + wdst), 16, 0, 0); \
      __builtin_amdgcn_global_load_lds(GLBP(Bt + bofs[i] + ko), LDSP(Bd + i * 4096 + wdst), 16, 0, 0);\
    }                                                                                                 \
  } while (0)
#define RD(afX, bqX, sl, cso) do {                                                                    \
    const u16* As_ = lds + ((sl) & 1) * 16384;                                                        \
    const u16* Bs_ = As_ + 8192;                                                                      \
    _Pragma("unroll")                                                                                 \
    for (int f = 0; f < 4; ++f) afX[f] = *(const bf16x8*)(As_ + arow[f] + (cso));                     \
    _Pragma("unroll")                                                                                 \
    for (int f = 0; f < 2; ++f) bqX[f] = *(const bf16x8*)(Bs_ + brow[f] + (cso));                     \
  } while (0)
#define MM(afX, bqX)                                                                                  \
  _Pragma("unroll") for (int nf = 0; nf < 2; ++nf)                                                    \
  _Pragma("unroll") for (int mf = 0; mf < 4; ++mf)                                                    \
    acc[mf][nf] = __builtin_amdgcn_mfma_f32_16x16x32_bf16(afX[mf], bqX[nf], acc[mf][nf], 0, 0, 0);

  bf16x8 afA[4], bqA[2], afB[4], bqB[2];

  STG(0);
  asm volatile("s_waitcnt vmcnt(0)" ::: "memory");
  __builtin_amdgcn_s_barrier();
  RD(afA, bqA, 0, cso0);
  asm volatile("s_waitcnt lgkmcnt(0)" ::: "memory");
  __builtin_amdgcn_sched_barrier(0);

  for (int s = 0; s < NS; ++s) {
    if (s + 1 < NS) STG(s + 1);
    RD(afB, bqB, s, cso1);
    __builtin_amdgcn_sched_barrier(0);
    __builtin_amdgcn_s_setprio(1);
    MM(afA, bqA);
    __builtin_amdgcn_s_setprio(0);
    asm volatile("s_waitcnt lgkmcnt(0)" ::: "memory");
    __builtin_amdgcn_sched_barrier(0);
    asm volatile("s_waitcnt vmcnt(0)" ::: "memory");
    __builtin_amdgcn_s_barrier();
    if (s + 1 < NS) RD(afA, bqA, s + 1, cso0);
    __builtin_amdgcn_sched_barrier(0);
    __builtin_amdgcn_s_setprio(1);
    MM(afB, bqB);
    __builtin_amdgcn_s_setprio(0);
    asm volatile("s_waitcnt lgkmcnt(0)" ::: "memory");
    __builtin_amdgcn_sched_barrier(0);
  }
#undef STG
#undef RD
#undef MM

  (void)Mr;
  if constexpr (EPI == 0) {
    const int obf = ODYN ? (flags[0] ? 0 : 1) : 0;
#pragma unroll
    for (int mf = 0; mf < 4; ++mf) {
#pragma unroll
      for (int nf = 0; nf < 2; ++nf) {
        const int col = tn + wc * 32 + nf * 16 + lr;
        const float bv = bias[col];
#pragma unroll
        for (int j = 0; j < 4; ++j) {
          const int rw = tm + wr * 64 + mf * 16 + lk * 4 + j;
          float vv = acc[mf][nf][j] + bv;
          if (RES) vv += res[(size_t)rw * N + col];
          if (GELU) vv = geluf(vv);
          if (WF) {
            if (ODYN && obf) ((u16*)outF)[(size_t)rw * N + col] = f2b(vv);
            else ((float*)outF)[(size_t)rw * N + col] = vv;
          }
          if (WB) outB[(size_t)rw * N + col] = f2b(vv);
        }
      }
    }
  } else {
    float* red = reinterpret_cast<float*>(lds);
    u16* vt = lds + 4096;
    float bv2[2];
#pragma unroll
    for (int nf = 0; nf < 2; ++nf) bv2[nf] = bias[tn + wc * 32 + nf * 16 + lr];
    float ss[4][4];
#pragma unroll
    for (int mf = 0; mf < 4; ++mf)
#pragma unroll
      for (int j = 0; j < 4; ++j) {
        float s = 0.f;
#pragma unroll
        for (int nf = 0; nf < 2; ++nf) {
          float v = acc[mf][nf][j] + bv2[nf];
          s += v * v;
        }
        s += __shfl_xor(s, 1); s += __shfl_xor(s, 2); s += __shfl_xor(s, 4); s += __shfl_xor(s, 8);
        ss[mf][j] = s;
      }
    if (lr == 0) {
#pragma unroll
      for (int mf = 0; mf < 4; ++mf)
#pragma unroll
        for (int j = 0; j < 4; ++j) {
          const int row = wr * 64 + mf * 16 + lk * 4 + j;
          red[row * 4 + wc] = ss[mf][j];
        }
    }
    __syncthreads();
    float rs[4][4];
#pragma unroll
    for (int mf = 0; mf < 4; ++mf)
#pragma unroll
      for (int j = 0; j < 4; ++j) {
        const int row = wr * 64 + mf * 16 + lk * 4 + j;
        rs[mf][j] = rsqrtf(red[row * 4 + 0] + red[row * 4 + 1] + red[row * 4 + 2] + red[row * 4 + 3] + 1e-12f);
      }
    if constexpr (EPI == 1) {
      const int h = tn >> 7;
#pragma unroll
      for (int mf = 0; mf < 4; ++mf)
#pragma unroll
        for (int nf = 0; nf < 2; ++nf) {
          const int d = wc * 32 + nf * 16 + lr;
#pragma unroll
          for (int j = 0; j < 4; ++j) {
            const int rw = tm + wr * 64 + mf * 16 + lk * 4 + j;
            const int sR = rw >> 1, bb = rw & 1;
            float v = (acc[mf][nf][j] + bv2[nf]) * rs[mf][j];
            outB[(((size_t)(bb * NH_ + h) * S_) + sR) * D_ + d] = f2b(v);
          }
        }
    } else {
      const int h = tn >> 8;
      const int isV = (tn >> 7) & 1;
      if (!isV) {
#pragma unroll
        for (int mf = 0; mf < 4; ++mf)
#pragma unroll
          for (int nf = 0; nf < 2; ++nf) {
            const int d = wc * 32 + nf * 16 + lr;
#pragma unroll
            for (int j = 0; j < 4; ++j) {
              const int rw = tm + wr * 64 + mf * 16 + lk * 4 + j;
              const int mR = rw >> 1, bb = rw & 1;
              float v = (acc[mf][nf][j] + bv2[nf]) * rs[mf][j];
              outB[(((size_t)(bb * NH_ + h) * M_) + mR) * D_ + d] = f2b(v);
            }
          }
      } else {
#pragma unroll
        for (int mf = 0; mf < 4; ++mf)
#pragma unroll
          for (int nf = 0; nf < 2; ++nf) {
            const int d = wc * 32 + nf * 16 + lr;
#pragma unroll
            for (int j = 0; j < 4; ++j) {
              const int rl = wr * 64 + mf * 16 + lk * 4 + j;
              float v = (acc[mf][nf][j] + bv2[nf]) * rs[mf][j];
              vt[((rl & 1) * 128 + d) * 72 + (rl >> 1)] = f2b(v);
            }
          }
        __syncthreads();
        const int dd = t >> 2, bb = (t >> 1) & 1, half = t & 1;
        const u16* src = vt + ((size_t)(bb * 128 + dd) * 72) + half * 32;
        u16* dst = (u16*)outF + (((size_t)(bb * NH_ + h) * D_ + dd) * M_) + (tm >> 1) + half * 32;
#pragma unroll
        for (int i = 0; i < 4; ++i) *(bf16x8*)&dst[i * 8] = *(const bf16x8*)&src[i * 8];
      }
    }
  }
}

// -------------------------------------------------------------- attention
// (256,4): VGPR 124 fits the 128 cap for 4 waves/SIMD; LDS 37KB fits 4
// blocks/CU -> explicit hint to reach 4 co-resident blocks (m114 TLP).
__global__ __launch_bounds__(256, 4) void attn_k(const u16* __restrict__ Q, const u16* __restrict__ Kq,
                                                 const u16* __restrict__ Vt, const u32* __restrict__ BM32,
                                                 u16* __restrict__ ctx) {
  __shared__ u16 Kl[2][4096];
  __shared__ u16 Vl[2][4096];
  __shared__ u16 Pl[4][16 * 40];
  const int t = threadIdx.x, w = t >> 6, l = t & 63, lr = l & 15, lk = l >> 4;
  const int lin = blockIdx.x;
  const int xcd = lin & 7, idx = lin >> 3;
  const int bh = xcd * 4 + (idx >> 5);
  const int chunk = idx & 31;
  const int b = bh >> 4, h = bh & 15;
  const int srow = chunk * 64 + w * 16;
  const u16* Qb = Q + ((size_t)bh * S_ + srow) * D_;
  bf16x8 qf[4];
#pragma unroll
  for (int kc = 0; kc < 4; ++kc)
    qf[kc] = *(const bf16x8*)&Qb[lr * D_ + kc * 32 + lk * 8];
  f32x4 oacc[8] = {};
  float den[4] = {};
  const u16* Kb = Kq + (size_t)bh * M_ * D_;
  const u16* Vb = Vt + (size_t)bh * D_ * M_;
  const float invn = 0.08838834764831845f;
  u32 ksrc[2], vsrc[2];
#pragma unroll
  for (int i = 0; i < 2; ++i) {
    const int kidx = i * 256 + t;
    const int kr = kidx >> 4, kc_ = (kidx & 15) ^ (kr & 7);
    ksrc[i] = (u32)kr * D_ + (u32)kc_ * 8;
    const int vidx = i * 256 + t;
    const int vd = vidx >> 2, vc = (vidx & 3) ^ ((vd >> 1) & 3);
    vsrc[i] = (u32)vd * M_ + (u32)vc * 8;
  }
  const int wdst = w * 64 * 8;
  u32 mrow[4];
#pragma unroll
  for (int j2 = 0; j2 < 4; ++j2)
    mrow[j2] = ((u32)b * S_ + (u32)(srow + lk * 4 + j2)) * 64u;

#define STG(buf, m0) do {                                                                              \
    _Pragma("unroll")                                                                                  \
    for (int i = 0; i < 2; ++i) {                                                                      \
      __builtin_amdgcn_global_load_lds(GLBP(Kb + (size_t)(m0) * D_ + ksrc[i]),                         \
                                       LDSP(&Kl[buf][i * 2048 + wdst]), 16, 0, 0);                     \
      __builtin_amdgcn_global_load_lds(GLBP(Vb + (size_t)(m0) + vsrc[i]),                              \
                                       LDSP(&Vl[buf][i * 2048 + wdst]), 16, 0, 0);                     \
    }                                                                                                  \
  } while (0)

  STG(0, 0);
  asm volatile("s_waitcnt vmcnt(0)" ::: "memory");
  __builtin_amdgcn_s_barrier();
  int cur = 0;

  for (int t64 = 0; t64 < M_ / 32; ++t64) {
    const int m0 = t64 * 32;
    if (t64 + 1 < M_ / 32) STG(cur ^ 1, m0 + 32);
    u32 mw[4];
#pragma unroll
    for (int j2 = 0; j2 < 4; ++j2) mw[j2] = BM32[mrow[j2] + t64];
    f32x4 sc[2] = {};
#pragma unroll
    for (int mf = 0; mf < 2; ++mf) {
      const int r = mf * 16 + lr;
#pragma unroll
      for (int kc = 0; kc < 4; ++kc) {
        const int cc = ((kc * 4 + lk) ^ (r & 7));
        bf16x8 kfv = *(const bf16x8*)&Kl[cur][r * 128 + cc * 8];
        sc[mf] = __builtin_amdgcn_mfma_f32_16x16x32_bf16(qf[kc], kfv, sc[mf], 0, 0, 0);
      }
    }
#pragma unroll
    for (int j2 = 0; j2 < 4; ++j2) {
      const int rloc = lk * 4 + j2;
#pragma unroll
      for (int mf = 0; mf < 2; ++mf) {
        float p = __expf(sc[mf][j2] * invn);
        p = ((mw[j2] >> (mf * 16 + lr)) & 1u) ? p : 0.0f;
        den[j2] += p;
        Pl[w][rloc * 40 + mf * 16 + lr] = f2b(p);
      }
    }
    asm volatile("s_waitcnt lgkmcnt(0)" ::: "memory");
    __builtin_amdgcn_sched_barrier(0);
    bf16x8 pa = *(const bf16x8*)&Pl[w][lr * 40 + lk * 8];
#pragma unroll
    for (int nf = 0; nf < 8; ++nf) {
      const int d = nf * 16 + lr;
      const int cc = lk ^ ((d >> 1) & 3);
      bf16x8 vfv = *(const bf16x8*)&Vl[cur][d * 32 + cc * 8];
      oacc[nf] = __builtin_amdgcn_mfma_f32_16x16x32_bf16(pa, vfv, oacc[nf], 0, 0, 0);
    }
    asm volatile("s_waitcnt vmcnt(0)" ::: "memory");
    __builtin_amdgcn_s_barrier();
    cur ^= 1;
  }
#undef STG
#pragma unroll
  for (int j2 = 0; j2 < 4; ++j2) {
    float d = den[j2];
    d += __shfl_xor(d, 1); d += __shfl_xor(d, 2); d += __shfl_xor(d, 4); d += __shfl_xor(d, 8);
    den[j2] = 1.0f / fmaxf(d, 1e-20f);
  }
#pragma unroll
  for (int nf = 0; nf < 8; ++nf)
#pragma unroll
    for (int j2 = 0; j2 < 4; ++j2) {
      const int s = srow + lk * 4 + j2;
      const int dd = nf * 16 + lr;
      ctx[((size_t)s * B_ + b) * H_ + h * D_ + dd] = f2b(oacc[nf][j2] * den[j2]);
    }
}

// ------------------------------------------------------------------- host
extern "C" void kernel_launch(void* const* d_in, const int* in_sizes, int n_in,
                              void* d_out, int out_size, void* d_ws, size_t ws_size,
                              hipStream_t stream) {
  (void)in_sizes; (void)n_in; (void)out_size; (void)ws_size;
  char* ws = (char*)d_ws;
  u16* WT     = (u16*)(ws + 0);
  void* MID   = (void*)(ws + 33554432);
  float* XF   = (float*)(ws + 100663296);
  u16* HB     = (u16*)(ws + 134217728);
  u16* MEMB   = (u16*)(ws + 150994944);
  u16* QB     = (u16*)(ws + 167772160);
  u16* KB     = (u16*)(ws + 184549376);
  u16* VTB    = (u16*)(ws + 201326592);
  u64* BMB    = (u64*)(ws + 218103808);
  float* SM   = (float*)(ws + 234881024);
  int* FLAGS  = (int*)(ws + 235044864);

  float* Bias1  = SM + 0;
  float* Bias1o = SM + 8192;
  float* BiasQ  = SM + 10240;
  float* BiasKV = SM + 12288;
  float* BiasD  = SM + 16384;
  float* Bias2  = SM + 18432;
  float* Bias2o = SM + 26624;
  float* G1v = SM + 28672; float* B1v = SM + 30720;
  float* G2v = SM + 32768; float* B2v = SM + 34816;
  float* G3v = SM + 36864; float* B3v = SM + 38912;

  detect_kinds<<<1, 64, 0, stream>>>((const u32*)d_in[0], (const u32*)d_in[2], FLAGS);

  cvt_all<<<160, 256, 0, stream>>>(d_in[10], d_in[12], d_in[14], d_in[16], d_in[18],
                                   d_in[20], d_in[22], d_in[3], d_in[4], d_in[5],
                                   d_in[6], d_in[7], d_in[8], FLAGS, SM);

  prep_k<<<20480, 256, 0, stream>>>(d_in[2], d_in[1], FLAGS, BMB, MEMB);

  dim3 blk(256);
  dim3 blk5(512);
  // ---- mlp1
  layernorm_k<1><<<SB_, blk, 0, stream>>>(d_in[0], FLAGS, G1v, B1v, HB);
  transpose_cast<<<dim3(FF_ / 64, H_ / 64), blk, 0, stream>>>(d_in[9], FLAGS, WT, H_, FF_);
  gemmra512<1, 0, 0, 1, 0, 0><<<dim3(FF_ / 128, SB_ / 128), blk5, 0, stream>>>(HB, WT, Bias1, nullptr, nullptr, (u16*)MID, FLAGS, SB_, FF_, H_);
  transpose_cast<<<dim3(H_ / 64, FF_ / 64), blk, 0, stream>>>(d_in[11], FLAGS, WT, FF_, H_);
  gemmra512<0, 0, 1, 0, 0, 0><<<dim3(H_ / 128, SB_ / 128), blk5, 0, stream>>>((u16*)MID, WT, Bias1o, nullptr, XF, nullptr, FLAGS, SB_, H_, FF_);

  // ---- memory attention
  layernorm_k<0><<<SB_, blk, 0, stream>>>(XF, FLAGS, G2v, B2v, HB);
  transpose_cast<<<dim3(H_ / 64, H_ / 64), blk, 0, stream>>>(d_in[13], FLAGS, WT, H_, H_);
  gemmra512<0, 0, 0, 0, 0, 1><<<dim3(H_ / 128, SB_ / 128), blk5, 0, stream>>>(HB, WT, BiasQ, nullptr, nullptr, QB, FLAGS, SB_, H_, H_);
  transpose_cast<<<dim3(2 * H_ / 64, H_ / 64), blk, 0, stream>>>(d_in[15], FLAGS, WT, H_, 2 * H_);
  gemmra512<0, 0, 0, 0, 0, 2><<<dim3(2 * H_ / 128, MB_ / 128), blk5, 0, stream>>>(MEMB, WT, BiasKV, nullptr, VTB, KB, FLAGS, MB_, 2 * H_, H_);
  attn_k<<<1024, blk, 0, stream>>>(QB, KB, VTB, (const u32*)BMB, MEMB);
  transpose_cast<<<dim3(H_ / 64, H_ / 64), blk, 0, stream>>>(d_in[17], FLAGS, WT, H_, H_);
  gemmra512<0, 1, 1, 0, 0, 0><<<dim3(H_ / 128, SB_ / 128), blk5, 0, stream>>>(MEMB, WT, BiasD, XF, XF, nullptr, FLAGS, SB_, H_, H_);

  // ---- mlp2
  layernorm_k<0><<<SB_, blk, 0, stream>>>(XF, FLAGS, G3v, B3v, HB);
  transpose_cast<<<dim3(FF_ / 64, H_ / 64), blk, 0, stream>>>(d_in[19], FLAGS, WT, H_, FF_);
  gemmra512<1, 0, 0, 1, 0, 0><<<dim3(FF_ / 128, SB_ / 128), blk5, 0, stream>>>(HB, WT, Bias2, nullptr, nullptr, (u16*)MID, FLAGS, SB_, FF_, H_);
  transpose_cast<<<dim3(H_ / 64, FF_ / 64), blk, 0, stream>>>(d_in[21], FLAGS, WT, FF_, H_);
  gemmra512<0, 1, 1, 0, 1, 0><<<dim3(H_ / 128, SB_ / 128), blk5, 0, stream>>>((u16*)MID, WT, Bias2o, XF, d_out, nullptr, FLAGS, SB_, H_, FF_);
}